// Round 4
// baseline (714.851 us; speedup 1.0000x reference)
//
#include <hip/hip_runtime.h>
#include <math.h>

typedef float f32x4 __attribute__((ext_vector_type(4)));
typedef short s16x8 __attribute__((ext_vector_type(8)));

#define N_TOT 16384
#define C_TOT 1000
#define C_PAD 1024
#define D_TOT 512
#define NC ((size_t)N_TOT * C_TOT)

#define EPS_F 1e-8f
#define SCALE_F 0.04419417382415922f  // 1/sqrt(512)

#define GL_LDS(gp, lp)                                                        \
    __builtin_amdgcn_global_load_lds(                                         \
        (const __attribute__((address_space(1))) void*)(gp),                  \
        (__attribute__((address_space(3))) void*)(lp), 16, 0, 0)

// ---------------- fsq / csq precompute: one wave per row ----------------
__global__ __launch_bounds__(256)
void sq_kernel(const float* __restrict__ F, const float* __restrict__ Cc,
               float* __restrict__ sqout) {
    int gw   = (blockIdx.x * 256 + threadIdx.x) >> 6;
    int lane = threadIdx.x & 63;
    if (gw >= N_TOT + C_TOT) return;
    const float* src = (gw < N_TOT) ? (F + (size_t)gw * D_TOT)
                                    : (Cc + (size_t)(gw - N_TOT) * D_TOT);
    f32x4 a = *(const f32x4*)(src + lane * 4);
    f32x4 b = *(const f32x4*)(src + 256 + lane * 4);
    float acc = a[0] * a[0];
    acc = fmaf(a[1], a[1], acc);
    acc = fmaf(a[2], a[2], acc);
    acc = fmaf(a[3], a[3], acc);
    acc = fmaf(b[0], b[0], acc);
    acc = fmaf(b[1], b[1], acc);
    acc = fmaf(b[2], b[2], acc);
    acc = fmaf(b[3], b[3], acc);
    #pragma unroll
    for (int off = 32; off > 0; off >>= 1)
        acc += __shfl_xor(acc, off);
    if (lane == 0) sqout[gw] = acc;
}

// ---------------- f32 -> bf16 (RNE) convert, C zero-padded to 1024 rows ----
__device__ inline short f2bf(float x) {
    union { float f; unsigned u; } v; v.f = x;
    unsigned r = (v.u + 0x7FFFu + ((v.u >> 16) & 1u)) >> 16;
    return (short)r;
}

__global__ __launch_bounds__(256)
void cvt_kernel(const float* __restrict__ F, const float* __restrict__ Cc,
                short* __restrict__ Fbf, short* __restrict__ Cbf) {
    const int FS8 = N_TOT * D_TOT / 8;   // 1048576
    const int CS8 = C_PAD * D_TOT / 8;   // 65536
    int gid = blockIdx.x * 256 + threadIdx.x;
    if (gid < FS8) {
        const float* s = F + (size_t)gid * 8;
        f32x4 a = *(const f32x4*)s;
        f32x4 b = *(const f32x4*)(s + 4);
        s16x8 o;
        o[0] = f2bf(a[0]); o[1] = f2bf(a[1]); o[2] = f2bf(a[2]); o[3] = f2bf(a[3]);
        o[4] = f2bf(b[0]); o[5] = f2bf(b[1]); o[6] = f2bf(b[2]); o[7] = f2bf(b[3]);
        *(s16x8*)(Fbf + (size_t)gid * 8) = o;
    } else if (gid < FS8 + CS8) {
        int j = gid - FS8;
        int base = j * 8;
        int crow = base >> 9;
        s16x8 o = (s16x8)(short)0;
        if (crow < C_TOT) {
            const float* s = Cc + (size_t)base;
            f32x4 a = *(const f32x4*)s;
            f32x4 b = *(const f32x4*)(s + 4);
            o[0] = f2bf(a[0]); o[1] = f2bf(a[1]); o[2] = f2bf(a[2]); o[3] = f2bf(a[3]);
            o[4] = f2bf(b[0]); o[5] = f2bf(b[1]); o[6] = f2bf(b[2]); o[7] = f2bf(b[3]);
        }
        *(s16x8*)(Cbf + (size_t)base) = o;
    }
}

// ---------------- bf16 MFMA dot GEMM -> writes L2 and cos directly ---------
// A = Fbf [16384][512], B = Cbf [1024][512] (B^T form). Tile 128x128, BK=32,
// 4 waves in 2x2, each wave 64x64 via 4x4 frags of 16x16x32.
// LDS rows of 32 bf16 (64 B); k-slot XOR-swizzled (slot ^ ((row>>1)&3)) on the
// GLOBAL source (linear global_load_lds dest), reader applies same XOR.
__global__ __launch_bounds__(256)
void dot_gemm(const short* __restrict__ Fbf, const short* __restrict__ Cbf,
              const float* __restrict__ sqbuf, float* __restrict__ out) {
    __shared__ short lds[2][8192];   // A: [0,4096), B: [4096,8192)

    const int tid  = threadIdx.x;
    const int lane = tid & 63;
    const int wid  = tid >> 6;
    const int wr   = wid >> 1;
    const int wc   = wid & 1;
    const int m0   = blockIdx.y * 128;
    const int n0   = blockIdx.x * 128;

    // staging: idx = tid (+256): row = idx>>2 (0..127), slot = idx&3
    const int row0 = tid >> 2;
    const int row1 = row0 + 64;
    const int slot = tid & 3;
    const int sw0  = slot ^ ((row0 >> 1) & 3);
    const int sw1  = slot ^ ((row1 >> 1) & 3);
    const short* sA0 = Fbf + (size_t)(m0 + row0) * D_TOT + sw0 * 8;
    const short* sA1 = Fbf + (size_t)(m0 + row1) * D_TOT + sw1 * 8;
    const short* sB0 = Cbf + (size_t)(n0 + row0) * D_TOT + sw0 * 8;
    const short* sB1 = Cbf + (size_t)(n0 + row1) * D_TOT + sw1 * 8;

    // fragment LDS offsets (elements), loop-invariant
    int offA[4], offB[4];
    #pragma unroll
    for (int fi = 0; fi < 4; ++fi) {
        int R = wr * 64 + fi * 16 + (lane & 15);
        offA[fi] = R * 32 + (((lane >> 4) ^ ((R >> 1) & 3)) << 3);
    }
    #pragma unroll
    for (int fj = 0; fj < 4; ++fj) {
        int R = wc * 64 + fj * 16 + (lane & 15);
        offB[fj] = 4096 + R * 32 + (((lane >> 4) ^ ((R >> 1) & 3)) << 3);
    }

    f32x4 acc[4][4];
    #pragma unroll
    for (int fi = 0; fi < 4; ++fi)
        #pragma unroll
        for (int fj = 0; fj < 4; ++fj) acc[fi][fj] = (f32x4)(0.f);

    GL_LDS(sA0, &lds[0][(size_t)tid * 8]);
    GL_LDS(sA1, &lds[0][(size_t)(tid + 256) * 8]);
    GL_LDS(sB0, &lds[0][4096 + (size_t)tid * 8]);
    GL_LDS(sB1, &lds[0][4096 + (size_t)(tid + 256) * 8]);
    __syncthreads();

    const int NK = D_TOT / 32;   // 16
    for (int kt = 0; kt < NK; ++kt) {
        if (kt + 1 < NK) {
            const int nb = (kt + 1) & 1;
            const int d1 = (kt + 1) * 32;
            GL_LDS(sA0 + d1, &lds[nb][(size_t)tid * 8]);
            GL_LDS(sA1 + d1, &lds[nb][(size_t)(tid + 256) * 8]);
            GL_LDS(sB0 + d1, &lds[nb][4096 + (size_t)tid * 8]);
            GL_LDS(sB1 + d1, &lds[nb][4096 + (size_t)(tid + 256) * 8]);
        }
        const short* lb = lds[kt & 1];
        s16x8 af[4], bg[4];
        #pragma unroll
        for (int fi = 0; fi < 4; ++fi) af[fi] = *(const s16x8*)&lb[offA[fi]];
        #pragma unroll
        for (int fj = 0; fj < 4; ++fj) bg[fj] = *(const s16x8*)&lb[offB[fj]];
        #pragma unroll
        for (int fi = 0; fi < 4; ++fi)
            #pragma unroll
            for (int fj = 0; fj < 4; ++fj)
                acc[fi][fj] = __builtin_amdgcn_mfma_f32_16x16x32_bf16(
                    af[fi], bg[fj], acc[fi][fj], 0, 0, 0);
        __syncthreads();
    }

    // epilogue: D layout col = lane&15, row = 4*(lane>>4) + reg  [m89/m91]
    const float* csq = sqbuf + N_TOT;
    float fs_[4][4], fn_[4][4];
    #pragma unroll
    for (int fi = 0; fi < 4; ++fi)
        #pragma unroll
        for (int reg = 0; reg < 4; ++reg) {
            int m = m0 + wr * 64 + fi * 16 + ((lane >> 4) << 2) + reg;
            float v = sqbuf[m];
            fs_[fi][reg] = v;
            fn_[fi][reg] = fmaxf(sqrtf(v), EPS_F);
        }
    #pragma unroll
    for (int fj = 0; fj < 4; ++fj) {
        int c = n0 + wc * 64 + fj * 16 + (lane & 15);
        if (c < C_TOT) {
            float cs = csq[c];
            float cn = fmaxf(sqrtf(cs), EPS_F);
            #pragma unroll
            for (int fi = 0; fi < 4; ++fi) {
                int mrow = m0 + wr * 64 + fi * 16 + ((lane >> 4) << 2);
                #pragma unroll
                for (int reg = 0; reg < 4; ++reg) {
                    float d = acc[fi][fj][reg];
                    size_t p = (size_t)(mrow + reg) * C_TOT + c;
                    float sqv = fmaxf(fs_[fi][reg] + cs - 2.0f * d, 0.f);
                    out[NC + p]     = sqrtf(sqv) * SCALE_F;
                    out[2 * NC + p] = (d * SCALE_F) / (fn_[fi][reg] * cn);
                }
            }
        }
    }
}

// ---------------- L1-only main kernel: tile 128x128, 8x8 per thread --------
__global__ __launch_bounds__(256)
void dist_main(const float* __restrict__ F, const float* __restrict__ Cc,
               float* __restrict__ out) {
    __shared__ float lds[2][256 * 16];  // rows 0..127 = F, 128..255 = C (16 f32/row)

    const int tid = threadIdx.x;
    const int tx  = tid & 15;
    const int ty  = tid >> 4;
    const int c0  = blockIdx.x * 128;
    const int n0  = blockIdx.y * 128;

    // staging: 4 chunks per thread; idx = tid + 256*r, row = idx>>2, slot = idx&3
    const int row  = tid >> 2;
    const int slot = tid & 3;
    const float* sF0 = F + (size_t)(n0 + row) * D_TOT + slot * 4;
    const float* sF1 = F + (size_t)(n0 + row + 64) * D_TOT + slot * 4;
    const int sw0 = slot ^ ((row >> 2) & 3);
    const int sw1 = slot ^ (((row + 64) >> 2) & 3);
    const float* sC0 = Cc + (size_t)(c0 + row) * D_TOT + sw0 * 4;
    const float* sC1 = Cc + (size_t)(c0 + row + 64) * D_TOT + sw1 * 4;
    const bool ok0 = (c0 + row) < C_TOT;
    const bool ok1 = (c0 + row + 64) < C_TOT;

    float l1[8][8];
    #pragma unroll
    for (int i = 0; i < 8; ++i)
        #pragma unroll
        for (int j = 0; j < 8; ++j) l1[i][j] = 0.f;

    GL_LDS(sF0, &lds[0][(size_t)tid * 4]);
    GL_LDS(sF1, &lds[0][(size_t)(tid + 256) * 4]);
    if (ok0) GL_LDS(sC0, &lds[0][(size_t)(tid + 512) * 4]);
    if (ok1) GL_LDS(sC1, &lds[0][(size_t)(tid + 768) * 4]);
    __syncthreads();

    const int NT  = D_TOT / 16;      // 32
    const int crs = (tx >> 2) & 3;   // reader-side c swizzle (j-independent)

    for (int t = 0; t < NT; ++t) {
        if (t + 1 < NT) {
            const int nb = (t + 1) & 1;
            const int d1 = (t + 1) * 16;
            GL_LDS(sF0 + d1, &lds[nb][(size_t)tid * 4]);
            GL_LDS(sF1 + d1, &lds[nb][(size_t)(tid + 256) * 4]);
            if (ok0) GL_LDS(sC0 + d1, &lds[nb][(size_t)(tid + 512) * 4]);
            if (ok1) GL_LDS(sC1 + d1, &lds[nb][(size_t)(tid + 768) * 4]);
        }

        const float* lf = &lds[t & 1][0];
        #pragma unroll
        for (int q = 0; q < 4; ++q) {
            const int cq = (q ^ crs) << 2;
            f32x4 cv[8];
            #pragma unroll
            for (int j = 0; j < 8; ++j)
                cv[j] = *(const f32x4*)&lf[(128 + tx + 16 * j) * 16 + cq];
            #pragma unroll
            for (int i = 0; i < 8; ++i) {
                f32x4 fv = *(const f32x4*)&lf[(ty + 16 * i) * 16 + (q << 2)];
                #pragma unroll
                for (int j = 0; j < 8; ++j)
                    #pragma unroll
                    for (int k = 0; k < 4; ++k) {
                        float d = fv[k] - cv[j][k];
                        l1[i][j] += fabsf(d);
                    }
            }
        }
        __syncthreads();
    }

    #pragma unroll
    for (int i = 0; i < 8; ++i) {
        const size_t rbase = (size_t)(n0 + ty + 16 * i) * C_TOT;
        #pragma unroll
        for (int j = 0; j < 8; ++j) {
            const int c = c0 + tx + 16 * j;
            if (c < C_TOT) out[rbase + c] = l1[i][j] * SCALE_F;
        }
    }
}

extern "C" void kernel_launch(void* const* d_in, const int* in_sizes, int n_in,
                              void* d_out, int out_size, void* d_ws, size_t ws_size,
                              hipStream_t stream) {
    const float* F  = (const float*)d_in[0];
    const float* Cc = (const float*)d_in[1];
    float* out   = (float*)d_out;
    float* sqbuf = (float*)d_ws;                 // [N_TOT + C_TOT] f32

    // bf16 scratch parked in the (not-yet-written) L1 region of out:
    // Fbf = 16384*512 bf16 (16.78 MB), Cbf = 1024*512 bf16 (1 MB)  < NC*4 B.
    short* Fbf = (short*)out;
    short* Cbf = Fbf + (size_t)N_TOT * D_TOT;

    int rows = N_TOT + C_TOT;
    sq_kernel<<<(rows + 3) / 4, 256, 0, stream>>>(F, Cc, sqbuf);
    cvt_kernel<<<(N_TOT * D_TOT / 8 + C_PAD * D_TOT / 8 + 255) / 256, 256, 0,
                 stream>>>(F, Cc, Fbf, Cbf);
    dot_gemm<<<dim3(8, 128), 256, 0, stream>>>(Fbf, Cbf, sqbuf, out);
    dist_main<<<dim3(8, 128), 256, 0, stream>>>(F, Cc, out);
}